// Round 11
// baseline (164.726 us; speedup 1.0000x reference)
//
#include <hip/hip_runtime.h>
#include <hip/hip_bf16.h>

#define N 16384
#define D 128
#define RS 16                        // row splits
#define CT 32                        // col tiles (N / 512)
#define ROWS_PER_SPLIT (N / RS)      // 1024
#define ITERS (ROWS_PER_SPLIT / 32)  // 32 iterations of 32 rows

typedef __attribute__((ext_vector_type(16))) float f32x16;
typedef long long i64;
typedef __attribute__((ext_vector_type(2))) long long i64x2;

// ---------------- Kernel A: normalize targets -> fp8 e4m3, fragment-permuted ----------------
// For 32x32x16 fp8 MFMA: lane l holds row/col (l&31), k = ks*16 + (l>>5)*8 + j.
// Store byte (row,k) at row*128 + ((k>>3)&1)*64 + (k>>4)*8 + (k&7): each lane's
// whole 8-MFMA fragment (64 bytes) is contiguous.
__global__ __launch_bounds__(256) void knorm(const float* __restrict__ t,
                                             unsigned char* __restrict__ bnq,
                                             unsigned* __restrict__ counter) {
    if (blockIdx.x == 0 && threadIdx.x == 0) *counter = 0;   // defensive re-zero
    const int row  = blockIdx.x * 4 + (threadIdx.x >> 6);
    const int lane = threadIdx.x & 63;
    const float2 v = *(const float2*)(t + (size_t)row * D + lane * 2);
    float ss = v.x * v.x + v.y * v.y;
#pragma unroll
    for (int m = 1; m <= 32; m <<= 1) ss += __shfl_xor(ss, m, 64);
    const float inv = rsqrtf(ss);
    const int k   = lane * 2;
    const int off = ((k >> 3) & 1) * 64 + (k >> 4) * 8 + (k & 7);
    const unsigned bits =
        (unsigned)__builtin_amdgcn_cvt_pk_fp8_f32(v.x * inv, v.y * inv, 0, false);
    *(unsigned short*)(bnq + (size_t)row * 128 + off) = (unsigned short)(bits & 0xFFFFu);
}

// ---------------- Kernel B: fused fp8 bn @ bn^T (32x32x16) + group-argmax ----------------
// R10 geometry (512 blocks x 4 waves, no LDS/barriers, XCD decode) with 32x32x16
// fp8 MFMA: half the MFMA instructions of 16x16x32 for the same FLOPs.
// fb[4][8] = 64 regs persistent; A double-buffered 16-reg frames (32 rows/iter).
// C layout: col=lane&31, row=(reg&3)+8*(reg>>2)+4*(lane>>5) -> reg group 4g..4g+3
// is 4 consecutive rows (base it*32+8g+4hi = 4*gid, gid = it*8+2g+hi, 0..255).
__global__ __launch_bounds__(256, 2) void kargmax(const unsigned char* __restrict__ bnq,
                                                  float* __restrict__ pval,
                                                  int* __restrict__ pcode) {
    const int tid  = threadIdx.x;
    const int lane = tid & 63;
    const int w    = tid >> 6;
    const int b    = blockIdx.x;
    const int s    = (b & 7) * 2 + ((b >> 3) & 1);   // 2 splits per XCD
    const int ct   = b >> 4;                          // 0..31
    const int j0w  = ct * 512 + w * 128;
    const int rbase = s * ROWS_PER_SPLIT;

    const int cl = lane & 31;      // row/col within 32
    const int hi = lane >> 5;      // k-half
    const int rloc = cl - 4 * hi;  // diag helper: diag when rloc == (r&3)+8*(r>>2)

    // persistent B fragments: 128 cols x 128 K, fp8 (4 col-tiles x 8 K-steps, 64 VGPRs)
    i64 fb[4][8];
#pragma unroll
    for (int c4 = 0; c4 < 4; ++c4)
#pragma unroll
        for (int ks = 0; ks < 8; ++ks)
            fb[c4][ks] = *(const i64*)(bnq + (size_t)(j0w + c4 * 32 + cl) * 128 +
                                       hi * 64 + ks * 8);

    const unsigned char* aptr = bnq + (size_t)(rbase + cl) * 128 + hi * 64;

    float mv[4];
#pragma unroll
    for (int c4 = 0; c4 < 4; ++c4) mv[c4] = -1e30f;
    unsigned gb = (unsigned)hi;        // gid = gb + 2*g; gb += 8 per iter

    const f32x16 z16 = {0.f,0.f,0.f,0.f,0.f,0.f,0.f,0.f,0.f,0.f,0.f,0.f,0.f,0.f,0.f,0.f};
    i64x2 fA[4], fB[4];

#define LOADF(buf, itv) do {                                  \
    const unsigned char* p_ = aptr + (size_t)(itv) * 4096;    \
    buf[0] = *(const i64x2*)(p_);                             \
    buf[1] = *(const i64x2*)(p_ + 16);                        \
    buf[2] = *(const i64x2*)(p_ + 32);                        \
    buf[3] = *(const i64x2*)(p_ + 48); } while (0)

#define COMPUTEF(buf, itv) do {                                                             \
    const int r0_ = rbase + (itv) * 32;                                                     \
    const bool dg_ = ((unsigned)(r0_ - j0w) < 128u);                                        \
    _Pragma("unroll")                                                                       \
    for (int c4 = 0; c4 < 4; ++c4) {                                                        \
        f32x16 acc;                                                                         \
        __builtin_amdgcn_s_setprio(1);                                                      \
        acc = __builtin_amdgcn_mfma_f32_32x32x16_fp8_fp8(buf[0][0], fb[c4][0], z16, 0, 0, 0); \
        acc = __builtin_amdgcn_mfma_f32_32x32x16_fp8_fp8(buf[0][1], fb[c4][1], acc, 0, 0, 0); \
        acc = __builtin_amdgcn_mfma_f32_32x32x16_fp8_fp8(buf[1][0], fb[c4][2], acc, 0, 0, 0); \
        acc = __builtin_amdgcn_mfma_f32_32x32x16_fp8_fp8(buf[1][1], fb[c4][3], acc, 0, 0, 0); \
        acc = __builtin_amdgcn_mfma_f32_32x32x16_fp8_fp8(buf[2][0], fb[c4][4], acc, 0, 0, 0); \
        acc = __builtin_amdgcn_mfma_f32_32x32x16_fp8_fp8(buf[2][1], fb[c4][5], acc, 0, 0, 0); \
        acc = __builtin_amdgcn_mfma_f32_32x32x16_fp8_fp8(buf[3][0], fb[c4][6], acc, 0, 0, 0); \
        acc = __builtin_amdgcn_mfma_f32_32x32x16_fp8_fp8(buf[3][1], fb[c4][7], acc, 0, 0, 0); \
        __builtin_amdgcn_s_setprio(0);                                                      \
        if (dg_ && r0_ == j0w + c4 * 32) {                                                  \
            _Pragma("unroll")                                                               \
            for (int r = 0; r < 16; ++r)                                                    \
                if (rloc == ((r & 3) + 8 * (r >> 2))) acc[r] -= 1.0f;                       \
        }                                                                                   \
        _Pragma("unroll")                                                                   \
        for (int g = 0; g < 4; ++g) {                                                       \
            const float g_ = fmaxf(fmaxf(acc[4*g], acc[4*g+1]),                             \
                                   fmaxf(acc[4*g+2], acc[4*g+3]));                          \
            const unsigned p_ = (__float_as_uint(g_) & 0xFFFFFF00u) | (gb + 2u * g);        \
            mv[c4] = fmaxf(mv[c4], __uint_as_float(p_));                                    \
        }                                                                                   \
    }                                                                                       \
    gb += 8u; } while (0)

    LOADF(fA, 0);
    LOADF(fB, 1);
    for (int it2 = 0; it2 < ITERS; it2 += 2) {
        COMPUTEF(fA, it2);     LOADF(fA, it2 + 2);   // overshoot -> pval pad, unused
        COMPUTEF(fB, it2 + 1); LOADF(fB, it2 + 3);
    }
#undef LOADF
#undef COMPUTEF

    // lanes l and l+32 share col cl: one packed fmax merges the k-halves
#pragma unroll
    for (int c4 = 0; c4 < 4; ++c4) {
        float v = mv[c4];
        v = fmaxf(v, __shfl_xor(v, 32, 64));
        if (lane < 32) {
            pval[(size_t)s * N + j0w + c4 * 32 + cl]  = v;
            pcode[(size_t)s * N + j0w + c4 * 32 + cl] =
                rbase + (int)(__float_as_uint(v) & 255u) * 4;
        }
    }
}

// ---------------- Kernel C: merge splits, fp32 re-rank, hinge, fused final mean ----------------
__global__ __launch_bounds__(256) void kloss(const float* __restrict__ q,
                                             const float* __restrict__ t,
                                             const float* __restrict__ pval,
                                             const int* __restrict__ pcode,
                                             float* __restrict__ bsum,
                                             unsigned* __restrict__ counter,
                                             float* __restrict__ out) {
    const int j    = blockIdx.x * 4 + (threadIdx.x >> 6);
    const int lane = threadIdx.x & 63;

    // merge the RS split winners (lane s holds split s)
    float v = -1e30f;
    int   c = 0;
    if (lane < RS) { v = pval[(size_t)lane * N + j]; c = pcode[(size_t)lane * N + j]; }
#pragma unroll
    for (int m = 1; m <= 8; m <<= 1) {
        const float ov = __shfl_xor(v, m, 64);
        const int   oc = __shfl_xor(c, m, 64);
        if (ov > v || (ov == v && oc < c)) { v = ov; c = oc; }
    }
    c = __shfl(c, 0, 64);

    const float2 qv = *(const float2*)(q + (size_t)j * D + lane * 2);
    const float2 tv = *(const float2*)(t + (size_t)j * D + lane * 2);
    float qq = qv.x * qv.x + qv.y * qv.y;
    float tt = tv.x * tv.x + tv.y * tv.y;
    float qt = qv.x * tv.x + qv.y * tv.y;
    float ww[4], wt[4], qw[4];
#pragma unroll
    for (int r = 0; r < 4; ++r) {
        const float2 wv = *(const float2*)(t + (size_t)(c + r) * D + lane * 2);
        ww[r] = wv.x * wv.x + wv.y * wv.y;
        wt[r] = wv.x * tv.x + wv.y * tv.y;
        qw[r] = wv.x * qv.x + wv.y * qv.y;
    }
#pragma unroll
    for (int m = 1; m <= 32; m <<= 1) {
        qq += __shfl_xor(qq, m, 64);
        tt += __shfl_xor(tt, m, 64);
        qt += __shfl_xor(qt, m, 64);
#pragma unroll
        for (int r = 0; r < 4; ++r) {
            ww[r] += __shfl_xor(ww[r], m, 64);
            wt[r] += __shfl_xor(wt[r], m, 64);
            qw[r] += __shfl_xor(qw[r], m, 64);
        }
    }
    const float pos = qt * rsqrtf(qq * tt);
    float best = -1e30f, neg = 0.f;
#pragma unroll
    for (int r = 0; r < 4; ++r) {
        float cr = wt[r] * rsqrtf(ww[r] * tt);
        if (c + r == j) cr -= 1.0f;              // diag candidate, matches sim - eye
        if (cr > best) { best = cr; neg = qw[r] * rsqrtf(qq * ww[r]); }
    }
    const float l = fmaxf(0.f, 1.0f - pos + neg);

    __shared__ float ls[4];
    __shared__ bool last;
    if (lane == 0) ls[threadIdx.x >> 6] = l;
    __syncthreads();
    if (threadIdx.x == 0) {
        bsum[blockIdx.x] = ls[0] + ls[1] + ls[2] + ls[3];
        __threadfence();
        last = (atomicAdd(counter, 1u) == gridDim.x - 1);
    }
    __syncthreads();
    if (last) {                                   // fused final mean (one block, fixed order)
        __threadfence();
        float sum = 0.f;
        for (int i = threadIdx.x; i < N / 4; i += 256) sum += bsum[i];
#pragma unroll
        for (int m = 1; m <= 32; m <<= 1) sum += __shfl_xor(sum, m, 64);
        __shared__ float ws2[4];
        if ((threadIdx.x & 63) == 0) ws2[threadIdx.x >> 6] = sum;
        __syncthreads();
        if (threadIdx.x == 0) {
            out[0] = (ws2[0] + ws2[1] + ws2[2] + ws2[3]) * (1.0f / N);
            *counter = 0;                         // self-reset for graph replay
        }
    }
}

extern "C" void kernel_launch(void* const* d_in, const int* in_sizes, int n_in,
                              void* d_out, int out_size, void* d_ws, size_t ws_size,
                              hipStream_t stream) {
    const float* q = (const float*)d_in[0];
    const float* t = (const float*)d_in[1];
    char* ws = (char*)d_ws;

    unsigned char* bnq = (unsigned char*)ws;                           // 2 MB (must stay first)
    float* pval = (float*)(ws + (size_t)N * 128);                      // 1 MB (also overshoot pad)
    int*   pcode = (int*)(ws + (size_t)N * 128 + (size_t)RS * N * 4);  // 1 MB
    float* bsum = (float*)(ws + (size_t)N * 128 + (size_t)2 * RS * N * 4); // 16 KB
    unsigned* counter = (unsigned*)(bsum + N / 4);                     // 4 B

    knorm<<<dim3(N / 4), dim3(256), 0, stream>>>(t, bnq, counter);
    kargmax<<<dim3(CT * RS), dim3(256), 0, stream>>>(bnq, pval, pcode);
    kloss<<<dim3(N / 4), dim3(256), 0, stream>>>(q, t, pval, pcode, bsum, counter,
                                                 (float*)d_out);
}

// Round 12
// 78.939 us; speedup vs baseline: 2.0867x; 2.0867x over previous
//
#include <hip/hip_runtime.h>
#include <hip/hip_bf16.h>

#define N 16384
#define D 128
#define RS 16                        // row splits
#define CT 32                        // col tiles (N / 512)
#define ROWS_PER_SPLIT (N / RS)      // 1024
#define ITERS (ROWS_PER_SPLIT / 32)  // 32 iterations of 32 rows

typedef __attribute__((ext_vector_type(16))) float f32x16;
typedef long long i64;
typedef __attribute__((ext_vector_type(2))) long long i64x2;

// ---------------- Kernel A: normalize targets -> fp8 e4m3, fragment-permuted ----------------
// For 32x32x16 fp8 MFMA: lane l holds row/col (l&31), k = ks*16 + (l>>5)*8 + j.
// Store byte (row,k) at row*128 + ((k>>3)&1)*64 + (k>>4)*8 + (k&7): each lane's
// whole 8-MFMA fragment (64 bytes) is contiguous.
__global__ __launch_bounds__(256) void knorm(const float* __restrict__ t,
                                             unsigned char* __restrict__ bnq) {
    const int row  = blockIdx.x * 4 + (threadIdx.x >> 6);
    const int lane = threadIdx.x & 63;
    const float2 v = *(const float2*)(t + (size_t)row * D + lane * 2);
    float ss = v.x * v.x + v.y * v.y;
#pragma unroll
    for (int m = 1; m <= 32; m <<= 1) ss += __shfl_xor(ss, m, 64);
    const float inv = rsqrtf(ss);
    const int k   = lane * 2;
    const int off = ((k >> 3) & 1) * 64 + (k >> 4) * 8 + (k & 7);
    const unsigned bits =
        (unsigned)__builtin_amdgcn_cvt_pk_fp8_f32(v.x * inv, v.y * inv, 0, false);
    *(unsigned short*)(bnq + (size_t)row * 128 + off) = (unsigned short)(bits & 0xFFFFu);
}

// ---------------- Kernel B: fused fp8 bn @ bn^T (32x32x16) + group-argmax ----------------
// R10 geometry (512 blocks x 4 waves, no LDS/barriers, XCD decode) with 32x32x16
// fp8 MFMA: half the MFMA instructions of 16x16x32 for the same FLOPs.
// fb[4][8] = 64 regs persistent; A double-buffered 16-reg frames (32 rows/iter).
// C layout: col=lane&31, row=(reg&3)+8*(reg>>2)+4*(lane>>5) -> reg group 4g..4g+3
// is 4 consecutive rows (base it*32+8g+4hi = 4*gid, gid = it*8+2g+hi, 0..255).
__global__ __launch_bounds__(256, 2) void kargmax(const unsigned char* __restrict__ bnq,
                                                  float* __restrict__ pval,
                                                  int* __restrict__ pcode) {
    const int tid  = threadIdx.x;
    const int lane = tid & 63;
    const int w    = tid >> 6;
    const int b    = blockIdx.x;
    const int s    = (b & 7) * 2 + ((b >> 3) & 1);   // 2 splits per XCD
    const int ct   = b >> 4;                          // 0..31
    const int j0w  = ct * 512 + w * 128;
    const int rbase = s * ROWS_PER_SPLIT;

    const int cl = lane & 31;      // row/col within 32
    const int hi = lane >> 5;      // k-half
    const int rloc = cl - 4 * hi;  // diag helper: diag when rloc == (r&3)+8*(r>>2)

    // persistent B fragments: 128 cols x 128 K, fp8 (4 col-tiles x 8 K-steps, 64 VGPRs)
    i64 fb[4][8];
#pragma unroll
    for (int c4 = 0; c4 < 4; ++c4)
#pragma unroll
        for (int ks = 0; ks < 8; ++ks)
            fb[c4][ks] = *(const i64*)(bnq + (size_t)(j0w + c4 * 32 + cl) * 128 +
                                       hi * 64 + ks * 8);

    const unsigned char* aptr = bnq + (size_t)(rbase + cl) * 128 + hi * 64;

    float mv[4];
#pragma unroll
    for (int c4 = 0; c4 < 4; ++c4) mv[c4] = -1e30f;
    unsigned gb = (unsigned)hi;        // gid = gb + 2*g; gb += 8 per iter

    const f32x16 z16 = {0.f,0.f,0.f,0.f,0.f,0.f,0.f,0.f,0.f,0.f,0.f,0.f,0.f,0.f,0.f,0.f};
    i64x2 fA[4], fB[4];

#define LOADF(buf, itv) do {                                  \
    const unsigned char* p_ = aptr + (size_t)(itv) * 4096;    \
    buf[0] = *(const i64x2*)(p_);                             \
    buf[1] = *(const i64x2*)(p_ + 16);                        \
    buf[2] = *(const i64x2*)(p_ + 32);                        \
    buf[3] = *(const i64x2*)(p_ + 48); } while (0)

#define COMPUTEF(buf, itv) do {                                                             \
    const int r0_ = rbase + (itv) * 32;                                                     \
    const bool dg_ = ((unsigned)(r0_ - j0w) < 128u);                                        \
    _Pragma("unroll")                                                                       \
    for (int c4 = 0; c4 < 4; ++c4) {                                                        \
        f32x16 acc;                                                                         \
        __builtin_amdgcn_s_setprio(1);                                                      \
        acc = __builtin_amdgcn_mfma_f32_32x32x16_fp8_fp8(buf[0][0], fb[c4][0], z16, 0, 0, 0); \
        acc = __builtin_amdgcn_mfma_f32_32x32x16_fp8_fp8(buf[0][1], fb[c4][1], acc, 0, 0, 0); \
        acc = __builtin_amdgcn_mfma_f32_32x32x16_fp8_fp8(buf[1][0], fb[c4][2], acc, 0, 0, 0); \
        acc = __builtin_amdgcn_mfma_f32_32x32x16_fp8_fp8(buf[1][1], fb[c4][3], acc, 0, 0, 0); \
        acc = __builtin_amdgcn_mfma_f32_32x32x16_fp8_fp8(buf[2][0], fb[c4][4], acc, 0, 0, 0); \
        acc = __builtin_amdgcn_mfma_f32_32x32x16_fp8_fp8(buf[2][1], fb[c4][5], acc, 0, 0, 0); \
        acc = __builtin_amdgcn_mfma_f32_32x32x16_fp8_fp8(buf[3][0], fb[c4][6], acc, 0, 0, 0); \
        acc = __builtin_amdgcn_mfma_f32_32x32x16_fp8_fp8(buf[3][1], fb[c4][7], acc, 0, 0, 0); \
        __builtin_amdgcn_s_setprio(0);                                                      \
        if (dg_ && r0_ == j0w + c4 * 32) {                                                  \
            _Pragma("unroll")                                                               \
            for (int r = 0; r < 16; ++r)                                                    \
                if (rloc == ((r & 3) + 8 * (r >> 2))) acc[r] -= 1.0f;                       \
        }                                                                                   \
        _Pragma("unroll")                                                                   \
        for (int g = 0; g < 4; ++g) {                                                       \
            const float g_ = fmaxf(fmaxf(acc[4*g], acc[4*g+1]),                             \
                                   fmaxf(acc[4*g+2], acc[4*g+3]));                          \
            const unsigned p_ = (__float_as_uint(g_) & 0xFFFFFF00u) | (gb + 2u * g);        \
            mv[c4] = fmaxf(mv[c4], __uint_as_float(p_));                                    \
        }                                                                                   \
    }                                                                                       \
    gb += 8u; } while (0)

    LOADF(fA, 0);
    LOADF(fB, 1);
    for (int it2 = 0; it2 < ITERS; it2 += 2) {
        COMPUTEF(fA, it2);     LOADF(fA, it2 + 2);   // overshoot -> pval pad, unused
        COMPUTEF(fB, it2 + 1); LOADF(fB, it2 + 3);
    }
#undef LOADF
#undef COMPUTEF

    // lanes l and l+32 share col cl: one packed fmax merges the k-halves
#pragma unroll
    for (int c4 = 0; c4 < 4; ++c4) {
        float v = mv[c4];
        v = fmaxf(v, __shfl_xor(v, 32, 64));
        if (lane < 32) {
            pval[(size_t)s * N + j0w + c4 * 32 + cl]  = v;
            pcode[(size_t)s * N + j0w + c4 * 32 + cl] =
                rbase + (int)(__float_as_uint(v) & 255u) * 4;
        }
    }
}

// ---------------- Kernel C: merge splits, re-rank 4 candidates in fp32, hinge ----------------
__global__ __launch_bounds__(256) void kloss(const float* __restrict__ q,
                                             const float* __restrict__ t,
                                             const float* __restrict__ pval,
                                             const int* __restrict__ pcode,
                                             float* __restrict__ bsum) {
    const int j    = blockIdx.x * 4 + (threadIdx.x >> 6);
    const int lane = threadIdx.x & 63;

    // merge the RS split winners (lane s holds split s)
    float v = -1e30f;
    int   c = 0;
    if (lane < RS) { v = pval[(size_t)lane * N + j]; c = pcode[(size_t)lane * N + j]; }
#pragma unroll
    for (int m = 1; m <= 8; m <<= 1) {
        const float ov = __shfl_xor(v, m, 64);
        const int   oc = __shfl_xor(c, m, 64);
        if (ov > v || (ov == v && oc < c)) { v = ov; c = oc; }
    }
    c = __shfl(c, 0, 64);

    const float2 qv = *(const float2*)(q + (size_t)j * D + lane * 2);
    const float2 tv = *(const float2*)(t + (size_t)j * D + lane * 2);
    float qq = qv.x * qv.x + qv.y * qv.y;
    float tt = tv.x * tv.x + tv.y * tv.y;
    float qt = qv.x * tv.x + qv.y * tv.y;
    float ww[4], wt[4], qw[4];
#pragma unroll
    for (int r = 0; r < 4; ++r) {
        const float2 wv = *(const float2*)(t + (size_t)(c + r) * D + lane * 2);
        ww[r] = wv.x * wv.x + wv.y * wv.y;
        wt[r] = wv.x * tv.x + wv.y * tv.y;
        qw[r] = wv.x * qv.x + wv.y * qv.y;
    }
#pragma unroll
    for (int m = 1; m <= 32; m <<= 1) {
        qq += __shfl_xor(qq, m, 64);
        tt += __shfl_xor(tt, m, 64);
        qt += __shfl_xor(qt, m, 64);
#pragma unroll
        for (int r = 0; r < 4; ++r) {
            ww[r] += __shfl_xor(ww[r], m, 64);
            wt[r] += __shfl_xor(wt[r], m, 64);
            qw[r] += __shfl_xor(qw[r], m, 64);
        }
    }
    const float pos = qt * rsqrtf(qq * tt);
    float best = -1e30f, neg = 0.f;
#pragma unroll
    for (int r = 0; r < 4; ++r) {
        float cr = wt[r] * rsqrtf(ww[r] * tt);
        if (c + r == j) cr -= 1.0f;              // diag candidate, matches sim - eye
        if (cr > best) { best = cr; neg = qw[r] * rsqrtf(qq * ww[r]); }
    }
    const float l = fmaxf(0.f, 1.0f - pos + neg);

    __shared__ float ls[4];
    if (lane == 0) ls[threadIdx.x >> 6] = l;
    __syncthreads();
    if (threadIdx.x == 0) bsum[blockIdx.x] = ls[0] + ls[1] + ls[2] + ls[3];
}

// ---------------- Kernel D: deterministic final mean ----------------
__global__ __launch_bounds__(256) void kfinal(const float* __restrict__ bsum,
                                              float* __restrict__ out) {
    float sum = 0.f;
    for (int i = threadIdx.x; i < N / 4; i += 256) sum += bsum[i];
#pragma unroll
    for (int m = 1; m <= 32; m <<= 1) sum += __shfl_xor(sum, m, 64);
    __shared__ float ws2[4];
    if ((threadIdx.x & 63) == 0) ws2[threadIdx.x >> 6] = sum;
    __syncthreads();
    if (threadIdx.x == 0) out[0] = (ws2[0] + ws2[1] + ws2[2] + ws2[3]) * (1.0f / N);
}

extern "C" void kernel_launch(void* const* d_in, const int* in_sizes, int n_in,
                              void* d_out, int out_size, void* d_ws, size_t ws_size,
                              hipStream_t stream) {
    const float* q = (const float*)d_in[0];
    const float* t = (const float*)d_in[1];
    char* ws = (char*)d_ws;

    unsigned char* bnq = (unsigned char*)ws;                           // 2 MB (must stay first)
    float* pval = (float*)(ws + (size_t)N * 128);                      // 1 MB (also overshoot pad)
    int*   pcode = (int*)(ws + (size_t)N * 128 + (size_t)RS * N * 4);  // 1 MB
    float* bsum = (float*)(ws + (size_t)N * 128 + (size_t)2 * RS * N * 4); // 16 KB

    knorm<<<dim3(N / 4), dim3(256), 0, stream>>>(t, bnq);
    kargmax<<<dim3(CT * RS), dim3(256), 0, stream>>>(bnq, pval, pcode);
    kloss<<<dim3(N / 4), dim3(256), 0, stream>>>(q, t, pval, pcode, bsum);
    kfinal<<<dim3(1), dim3(256), 0, stream>>>(bsum, (float*)d_out);
}